// Round 1
// baseline (175.814 us; speedup 1.0000x reference)
//
#include <hip/hip_runtime.h>
#include <math.h>

// Problem constants
#define DD    2048
#define EE    64
#define NTOK  8192
#define NCOL  128               // 64 gate cols | 64 noise cols
#define NR    32                // rounds of 64 k
#define BM    32                // tokens per block

// Output layout (all read back as float32 by harness)
#define PROB_OFF 0
#define IDX_OFF  524288
#define MASK_OFF 540672
#define MASK_K_STRIDE (NTOK * EE)

typedef __bf16 bf16x8 __attribute__((ext_vector_type(8)));
typedef float  f32x16 __attribute__((ext_vector_type(16)));

__device__ __forceinline__ unsigned f2bf_rne(float f) {
  unsigned u = __float_as_uint(f);
  return (u + 0x7fffu + ((u >> 16) & 1u)) >> 16;   // low 16 bits = bf16
}
__device__ __forceinline__ float bf2f(unsigned h) {
  return __uint_as_float(h << 16);
}

// ---------------------------------------------------------------------------
// prep_w: weights -> MFMA-fragment-ready bf16 hi/lo in workspace (1 MB).
// Fragment bijection (MUST match A-side staging in router_fused):
//   slot (g, nt, mat, lane, i)  <->  B[k][c],  k = 16*g + 8*(lane>>5) + i,
//   c = 32*nt + (lane&31),  (c<64 -> gate, else noise).
// Byte addr = ((g*4 + nt)*2 + mat)*1024 + lane*16 + 2*i.
// Round r's 4 g-steps are contiguous 32 KB at ws + r*32768 -> linear staging.
// ---------------------------------------------------------------------------
__global__ __launch_bounds__(256) void prep_w(
    const float* __restrict__ wg, const float* __restrict__ wn,
    unsigned char* __restrict__ wsb)
{
  const int t  = blockIdx.x * 256 + threadIdx.x;   // 0..32767
  const int l  = t & 63;
  const int nt = (t >> 6) & 3;
  const int g  = t >> 8;                           // 0..127 (16-k steps)
  const int colg = nt * 32 + (l & 31);             // 0..127
  const int kb   = g * 16 + 8 * (l >> 5);
  const float* wsrc = (colg < EE) ? (wg + colg) : (wn + (colg - EE));

  unsigned hv[8], lv[8];
#pragma unroll
  for (int i = 0; i < 8; ++i) {
    const float v = wsrc[(size_t)(kb + i) * EE];
    const unsigned h = f2bf_rne(v);
    hv[i] = h;
    lv[i] = f2bf_rne(v - bf2f(h));
  }
  uint4 hq, lq;
  hq.x = hv[0] | (hv[1] << 16); hq.y = hv[2] | (hv[3] << 16);
  hq.z = hv[4] | (hv[5] << 16); hq.w = hv[6] | (hv[7] << 16);
  lq.x = lv[0] | (lv[1] << 16); lq.y = lv[2] | (lv[3] << 16);
  lq.z = lv[4] | (lv[5] << 16); lq.w = lv[6] | (lv[7] << 16);

  const size_t base = ((size_t)(g * 4 + nt) * 2) * 1024 + (size_t)l * 16;
  *reinterpret_cast<uint4*>(wsb + base)        = hq;   // hi
  *reinterpret_cast<uint4*>(wsb + base + 1024) = lq;   // lo
}

// ---------------------------------------------------------------------------
// router_fused: GEMM (bf16 hi/lo-split, 3x mfma_32x32x16) + top-2 epilogue.
// 256 blocks x 512 thr (8 waves). Block = 32 tokens, 128 cols, full K=2048.
// Wave wid: nt = wid&3 (32-col tile), kh = wid>>2 (K-half of each round).
// Per 64-k round: x reg-staged (fp32->hi/lo inline) into 8 KB A-frag buf;
// B linearly copied from ws (32 KB). Double-buffered, one barrier/round
// (m97-proven macro pipeline). After k-loop: kh-reduce via LDS logits
// [32][128], then per-wave shuffle top-2 (4 tokens/wave), scatter outputs.
// ---------------------------------------------------------------------------
__global__ __launch_bounds__(512) void router_fused(
    const float* __restrict__ x,
    const float* __restrict__ noise_eps,
    const unsigned char* __restrict__ wsb,
    float* __restrict__ out)
{
  // LDS: A frags 2 x 8 KB | B frags 2 x 32 KB  (80 KB). Logits [32][128] f32
  // (16 KB) overlays the A region after the k-loop.
  __shared__ uint4 lds_u4[(16384 + 65536) / 16];
  char* lds  = reinterpret_cast<char*>(lds_u4);
  char* ldsA = lds;
  char* ldsB = lds + 16384;

  const int tid  = threadIdx.x;
  const int wid  = tid >> 6;
  const int lane = tid & 63;
  const int nt   = wid & 3;
  const int kh   = wid >> 2;
  const int tok0 = blockIdx.x * BM;

  // ---- A staging role: 512 thr x 1 float4 = 32 tok x 64 k per round ----
  // t = aks(2b) | al(6b) | ah(1b):  element (kidx=aks, lane=al, i=4*ah+j)
  //   <-> x[tok0 + (al&31)][64r + 16*aks + 8*(al>>5) + 4*ah + j]
  const int aks = tid >> 7;             // 0..3
  const int al  = (tid & 127) >> 1;     // 0..63
  const int ah  = tid & 1;
  const float* ax = x + (size_t)(tok0 + (al & 31)) * DD
                      + 16 * aks + 8 * (al >> 5) + 4 * ah;
  const int aoff_hi = ((aks * 2 + 0) * 64 + al) * 16 + ah * 8;
  const int aoff_lo = ((aks * 2 + 1) * 64 + al) * 16 + ah * 8;

  // ---- B staging role: wave wid copies bytes [wid*4096, wid*4096+4096) ----
  const int boff = wid * 4096 + lane * 16;   // + j*1024, j=0..3

  // inline fp32 -> packed bf16 hi/lo, ds_write_b64 x2
  auto stage_a = [&](const float4& v, char* abuf) {
    const unsigned h0 = f2bf_rne(v.x), h1 = f2bf_rne(v.y),
                   h2 = f2bf_rne(v.z), h3 = f2bf_rne(v.w);
    uint2 hp, lp;
    hp.x = h0 | (h1 << 16); hp.y = h2 | (h3 << 16);
    lp.x = f2bf_rne(v.x - bf2f(h0)) | (f2bf_rne(v.y - bf2f(h1)) << 16);
    lp.y = f2bf_rne(v.z - bf2f(h2)) | (f2bf_rne(v.w - bf2f(h3)) << 16);
    *reinterpret_cast<uint2*>(abuf + aoff_hi) = hp;
    *reinterpret_cast<uint2*>(abuf + aoff_lo) = lp;
  };

  // ---- prologue: stage round 0 direct, load round 1 into regs ----
  {
    const float4 v = *reinterpret_cast<const float4*>(ax);
    stage_a(v, ldsA);
#pragma unroll
    for (int j = 0; j < 4; ++j) {
      const uint4 b = *reinterpret_cast<const uint4*>(wsb + boff + j * 1024);
      *reinterpret_cast<uint4*>(ldsB + boff + j * 1024) = b;
    }
  }
  float4 xr = *reinterpret_cast<const float4*>(ax + 64);
  uint4 br[4];
#pragma unroll
  for (int j = 0; j < 4; ++j)
    br[j] = *reinterpret_cast<const uint4*>(wsb + 32768 + boff + j * 1024);
  __syncthreads();

  f32x16 acc = {0.f,0.f,0.f,0.f,0.f,0.f,0.f,0.f,
                0.f,0.f,0.f,0.f,0.f,0.f,0.f,0.f};

  for (int r = 0; r < NR; ++r) {
    const int cur = r & 1, nxt = cur ^ 1;

    if (r + 1 < NR) {
      // write staged round r+1 into the other buffer
      stage_a(xr, ldsA + nxt * 8192);
#pragma unroll
      for (int j = 0; j < 4; ++j)
        *reinterpret_cast<uint4*>(ldsB + nxt * 32768 + boff + j * 1024) = br[j];
      // prefetch round r+2 into regs (x: HBM, B: L2-resident ws)
      if (r + 2 < NR) {
        xr = *reinterpret_cast<const float4*>(ax + (size_t)64 * (r + 2));
#pragma unroll
        for (int j = 0; j < 4; ++j)
          br[j] = *reinterpret_cast<const uint4*>(
              wsb + (size_t)(r + 2) * 32768 + boff + j * 1024);
      }
      __builtin_amdgcn_sched_barrier(0);
    }

    // ---- compute: wave (nt, kh): 2 ksteps x {hi*hi, hi*lo, lo*hi} ----
    const char* Ab = ldsA + cur * 8192;
    const char* Bb = ldsB + cur * 32768;
#pragma unroll
    for (int s = 0; s < 2; ++s) {
      const int kidx = kh * 2 + s;
      const bf16x8 ahi = *reinterpret_cast<const bf16x8*>(
          Ab + ((kidx * 2 + 0) * 64 + lane) * 16);
      const bf16x8 alo = *reinterpret_cast<const bf16x8*>(
          Ab + ((kidx * 2 + 1) * 64 + lane) * 16);
      const bf16x8 bhi = *reinterpret_cast<const bf16x8*>(
          Bb + ((kidx * 4 + nt) * 2 + 0) * 1024 + lane * 16);
      const bf16x8 blo = *reinterpret_cast<const bf16x8*>(
          Bb + ((kidx * 4 + nt) * 2 + 1) * 1024 + lane * 16);
      acc = __builtin_amdgcn_mfma_f32_32x32x16_bf16(ahi, bhi, acc, 0, 0, 0);
      acc = __builtin_amdgcn_mfma_f32_32x32x16_bf16(ahi, blo, acc, 0, 0, 0);
      acc = __builtin_amdgcn_mfma_f32_32x32x16_bf16(alo, bhi, acc, 0, 0, 0);
    }
    __syncthreads();
  }

  // ---- kh-reduce into logits L[32][128] (overlays A region) ----
  // C/D map (verified m74/m101): col = lane&31, row = (q&3)+8*(q>>2)+4*(lane>>5)
  float* L = reinterpret_cast<float*>(lds);
  const int ccol  = nt * 32 + (lane & 31);
  const int crow0 = 4 * (lane >> 5);
  if (kh == 0) {
#pragma unroll
    for (int q = 0; q < 16; ++q)
      L[((q & 3) + 8 * (q >> 2) + crow0) * 128 + ccol] = acc[q];
  }
  __syncthreads();
  if (kh == 1) {
#pragma unroll
    for (int q = 0; q < 16; ++q)
      L[((q & 3) + 8 * (q >> 2) + crow0) * 128 + ccol] += acc[q];
  }
  __syncthreads();

  // ---- epilogue: 8 waves x 4 tokens; lane = expert ----
#pragma unroll
  for (int it = 0; it < 4; ++it) {
    const int tl  = wid * 4 + it;
    const int tok = tok0 + tl;

    const float g    = L[tl * 128 + lane];
    const float nraw = L[tl * 128 + 64 + lane];
    const float ep   = noise_eps[(size_t)tok * EE + lane];

    const float sp = fmaxf(nraw, 0.0f) + log1pf(expf(-fabsf(nraw)));
    const float z  = fmaf(sp, ep, g);

    float v1 = z; int i1 = lane;
#pragma unroll
    for (int off = 32; off >= 1; off >>= 1) {
      const float ov = __shfl_xor(v1, off, 64);
      const int   oi = __shfl_xor(i1, off, 64);
      if (ov > v1 || (ov == v1 && oi < i1)) { v1 = ov; i1 = oi; }
    }
    float v2 = (lane == i1) ? -INFINITY : z; int i2 = lane;
#pragma unroll
    for (int off = 32; off >= 1; off >>= 1) {
      const float ov = __shfl_xor(v2, off, 64);
      const int   oi = __shfl_xor(i2, off, 64);
      if (ov > v2 || (ov == v2 && oi < i2)) { v2 = ov; i2 = oi; }
    }

    const float e2 = expf(v2 - v1);
    const float denom = 1.0f + e2;
    const float p1 = 1.0f / denom;
    const float p2 = e2 / denom;

    out[PROB_OFF + (size_t)tok * EE + lane] =
        (lane == i1) ? p1 : ((lane == i2) ? p2 : 0.0f);
    if (lane == 0) {
      out[IDX_OFF + tok * 2 + 0] = (float)i1;
      out[IDX_OFF + tok * 2 + 1] = (float)i2;
    }
    out[MASK_OFF + 0 * MASK_K_STRIDE + (size_t)tok * EE + lane] =
        (lane == i1) ? 1.0f : 0.0f;
    out[MASK_OFF + 1 * MASK_K_STRIDE + (size_t)tok * EE + lane] =
        (lane == i2) ? 1.0f : 0.0f;
  }
}

// ---------------------------------------------------------------------------
extern "C" void kernel_launch(void* const* d_in, const int* in_sizes, int n_in,
                              void* d_out, int out_size, void* d_ws, size_t ws_size,
                              hipStream_t stream) {
  const float* x   = (const float*)d_in[0];
  const float* eps = (const float*)d_in[1];
  const float* wg  = (const float*)d_in[2];
  const float* wn  = (const float*)d_in[3];
  unsigned char* wsb = (unsigned char*)d_ws;   // 1 MB bf16 hi/lo weight frags

  prep_w<<<dim3(128), dim3(256), 0, stream>>>(wg, wn, wsb);
  router_fused<<<dim3(NTOK / BM), dim3(512), 0, stream>>>(x, eps, wsb,
                                                          (float*)d_out);
}

// Round 2
// 138.287 us; speedup vs baseline: 1.2714x; 1.2714x over previous
//
#include <hip/hip_runtime.h>
#include <math.h>

// Problem constants
#define DD    2048
#define EE    64
#define NTOK  8192
#define BM    32                // tokens per block
#define NKS   32                // ksteps (of 16 k) per kh-wave; 4 kh * 32 * 16 = 2048

// Output layout (all read back as float32 by harness)
#define PROB_OFF 0
#define IDX_OFF  524288
#define MASK_OFF 540672
#define MASK_K_STRIDE (NTOK * EE)

typedef __bf16 bf16x8 __attribute__((ext_vector_type(8)));
typedef float  f32x16 __attribute__((ext_vector_type(16)));

__device__ __forceinline__ unsigned f2bf_rne(float f) {
  unsigned u = __float_as_uint(f);
  return (u + 0x7fffu + ((u >> 16) & 1u)) >> 16;   // low 16 bits = bf16
}
__device__ __forceinline__ float bf2f(unsigned h) {
  return __uint_as_float(h << 16);
}

// ---------------------------------------------------------------------------
// prep_w: weights -> MFMA-fragment-ready bf16 hi/lo in workspace (1 MB).
// Fragment bijection (validated end-to-end by round-1 pass):
//   slot (g, nt, mat, lane, i)  <->  B[k][c],  k = 16*g + 8*(lane>>5) + i,
//   c = 32*nt + (lane&31),  (c<64 -> gate, else noise).
// Byte addr = ((g*4 + nt)*2 + mat)*1024 + lane*16 + 2*i.
// ---------------------------------------------------------------------------
__global__ __launch_bounds__(256) void prep_w(
    const float* __restrict__ wg, const float* __restrict__ wn,
    unsigned char* __restrict__ wsb)
{
  const int t  = blockIdx.x * 256 + threadIdx.x;   // 0..32767
  const int l  = t & 63;
  const int nt = (t >> 6) & 3;
  const int g  = t >> 8;                           // 0..127 (16-k steps)
  const int colg = nt * 32 + (l & 31);             // 0..127
  const int kb   = g * 16 + 8 * (l >> 5);
  const float* wsrc = (colg < EE) ? (wg + colg) : (wn + (colg - EE));

  unsigned hv[8], lv[8];
#pragma unroll
  for (int i = 0; i < 8; ++i) {
    const float v = wsrc[(size_t)(kb + i) * EE];
    const unsigned h = f2bf_rne(v);
    hv[i] = h;
    lv[i] = f2bf_rne(v - bf2f(h));
  }
  uint4 hq, lq;
  hq.x = hv[0] | (hv[1] << 16); hq.y = hv[2] | (hv[3] << 16);
  hq.z = hv[4] | (hv[5] << 16); hq.w = hv[6] | (hv[7] << 16);
  lq.x = lv[0] | (lv[1] << 16); lq.y = lv[2] | (lv[3] << 16);
  lq.z = lv[4] | (lv[5] << 16); lq.w = lv[6] | (lv[7] << 16);

  const size_t base = ((size_t)(g * 4 + nt) * 2) * 1024 + (size_t)l * 16;
  *reinterpret_cast<uint4*>(wsb + base)        = hq;   // hi
  *reinterpret_cast<uint4*>(wsb + base + 1024) = lq;   // lo
}

// ---------------------------------------------------------------------------
// router_fused v2: barrier-free k-loop. 256 blocks x 1024 thr (16 waves =
// 4 nt x 4 kh). Each wave owns a 32tok x 32col x 512k slice, fully
// independent: per 16-k step it loads its A data straight from x (32 full
// 64B lines/wave, line-exact), converts fp32->bf16 hi/lo in-register, loads
// its B hi/lo fragment straight from L2-resident ws (1KB/wave coalesced),
// and issues 4 mfma_32x32x16 (hi*hi + hi*lo + lo*hi + lo*lo). Depth-2
// register prefetch; no LDS, no __syncthreads until the final kh-reduce.
// ---------------------------------------------------------------------------
struct KSet { float4 xa, xb; uint4 bh, bl; };

union BF8 { bf16x8 v; ushort u[8]; };

__device__ __forceinline__ void cvt_hilo(const float4& a, const float4& b,
                                         bf16x8& hi, bf16x8& lo) {
  const float f[8] = {a.x, a.y, a.z, a.w, b.x, b.y, b.z, b.w};
  BF8 H, L;
#pragma unroll
  for (int i = 0; i < 8; ++i) {
    const unsigned u = __float_as_uint(f[i]);
    H.u[i] = (ushort)(u >> 16);                                // trunc: exact prefix
    L.v[i] = (__bf16)(f[i] - __uint_as_float(u & 0xffff0000u)); // exact residual, RNE
  }
  hi = H.v; lo = L.v;
}

__global__ __launch_bounds__(1024, 4) void router_fused(
    const float* __restrict__ x,
    const float* __restrict__ noise_eps,
    const unsigned char* __restrict__ wsb,
    float* __restrict__ out)
{
  __shared__ float Lp[4][BM][128];   // 64 KB kh-partials; only used post-loop

  const int tid  = threadIdx.x;
  const int wid  = tid >> 6;          // 0..15
  const int lane = tid & 63;
  const int nt   = wid & 3;           // 32-col tile
  const int kh   = wid >> 2;          // K quarter (512 k)
  const int tok0 = blockIdx.x * BM;

  // A source: lane l -> x[tok0+(l&31)][kh*512 + 16*s + 8*(l>>5) + 0..7]
  const float* xp = x + (size_t)(tok0 + (lane & 31)) * DD
                      + kh * 512 + 8 * (lane >> 5);
  // B source: g = kh*32 + s; bytes ((g*4+nt)*2)*1024 + lane*16 (+1024 for lo)
  const unsigned char* bp = wsb + ((size_t)(kh * 32) * 4 + nt) * 2048
                                + (size_t)lane * 16;

  auto LOAD = [&](int s) {
    KSet k;
    const float* p = xp + 16 * s;
    k.xa = *reinterpret_cast<const float4*>(p);
    k.xb = *reinterpret_cast<const float4*>(p + 4);
    const unsigned char* q = bp + (size_t)8192 * s;
    k.bh = *reinterpret_cast<const uint4*>(q);
    k.bl = *reinterpret_cast<const uint4*>(q + 1024);
    return k;
  };

  f32x16 acc = {0.f,0.f,0.f,0.f,0.f,0.f,0.f,0.f,
                0.f,0.f,0.f,0.f,0.f,0.f,0.f,0.f};

  auto COMPUTE = [&](const KSet& k) {
    bf16x8 ahi, alo;
    cvt_hilo(k.xa, k.xb, ahi, alo);
    const bf16x8 bhi = __builtin_bit_cast(bf16x8, k.bh);
    const bf16x8 blo = __builtin_bit_cast(bf16x8, k.bl);
    acc = __builtin_amdgcn_mfma_f32_32x32x16_bf16(ahi, bhi, acc, 0, 0, 0);
    acc = __builtin_amdgcn_mfma_f32_32x32x16_bf16(ahi, blo, acc, 0, 0, 0);
    acc = __builtin_amdgcn_mfma_f32_32x32x16_bf16(alo, bhi, acc, 0, 0, 0);
    acc = __builtin_amdgcn_mfma_f32_32x32x16_bf16(alo, blo, acc, 0, 0, 0);
  };

  // depth-2 register pipeline, no barriers
  KSet a = LOAD(0), b = LOAD(1);
#pragma unroll 1
  for (int s = 0; s < NKS - 2; s += 2) {
    KSet t0 = LOAD(s + 2);
    COMPUTE(a);
    a = t0;
    KSet t1 = LOAD(s + 3);
    COMPUTE(b);
    b = t1;
  }
  COMPUTE(a);
  COMPUTE(b);

  // ---- kh-reduce: C/D map (validated R1): col = lane&31,
  // row = (q&3) + 8*(q>>2) + 4*(lane>>5) ----
  const int ccol  = nt * 32 + (lane & 31);
  const int crow0 = 4 * (lane >> 5);
#pragma unroll
  for (int q = 0; q < 16; ++q)
    Lp[kh][(q & 3) + 8 * (q >> 2) + crow0][ccol] = acc[q];
  __syncthreads();

  // ---- epilogue: 16 waves x 2 tokens; lane = expert ----
#pragma unroll
  for (int it = 0; it < 2; ++it) {
    const int tl  = wid * 2 + it;
    const int tok = tok0 + tl;

    const float g    = Lp[0][tl][lane] + Lp[1][tl][lane]
                     + Lp[2][tl][lane] + Lp[3][tl][lane];
    const float nraw = Lp[0][tl][64 + lane] + Lp[1][tl][64 + lane]
                     + Lp[2][tl][64 + lane] + Lp[3][tl][64 + lane];
    const float ep   = noise_eps[(size_t)tok * EE + lane];

    const float sp = fmaxf(nraw, 0.0f) + log1pf(expf(-fabsf(nraw)));
    const float z  = fmaf(sp, ep, g);

    float v1 = z; int i1 = lane;
#pragma unroll
    for (int off = 32; off >= 1; off >>= 1) {
      const float ov = __shfl_xor(v1, off, 64);
      const int   oi = __shfl_xor(i1, off, 64);
      if (ov > v1 || (ov == v1 && oi < i1)) { v1 = ov; i1 = oi; }
    }
    float v2 = (lane == i1) ? -INFINITY : z; int i2 = lane;
#pragma unroll
    for (int off = 32; off >= 1; off >>= 1) {
      const float ov = __shfl_xor(v2, off, 64);
      const int   oi = __shfl_xor(i2, off, 64);
      if (ov > v2 || (ov == v2 && oi < i2)) { v2 = ov; i2 = oi; }
    }

    const float e2 = expf(v2 - v1);
    const float denom = 1.0f + e2;
    const float p1 = 1.0f / denom;
    const float p2 = e2 / denom;

    out[PROB_OFF + (size_t)tok * EE + lane] =
        (lane == i1) ? p1 : ((lane == i2) ? p2 : 0.0f);
    if (lane == 0) {
      out[IDX_OFF + tok * 2 + 0] = (float)i1;
      out[IDX_OFF + tok * 2 + 1] = (float)i2;
    }
    out[MASK_OFF + 0 * MASK_K_STRIDE + (size_t)tok * EE + lane] =
        (lane == i1) ? 1.0f : 0.0f;
    out[MASK_OFF + 1 * MASK_K_STRIDE + (size_t)tok * EE + lane] =
        (lane == i2) ? 1.0f : 0.0f;
  }
}

// ---------------------------------------------------------------------------
extern "C" void kernel_launch(void* const* d_in, const int* in_sizes, int n_in,
                              void* d_out, int out_size, void* d_ws, size_t ws_size,
                              hipStream_t stream) {
  const float* x   = (const float*)d_in[0];
  const float* eps = (const float*)d_in[1];
  const float* wg  = (const float*)d_in[2];
  const float* wn  = (const float*)d_in[3];
  unsigned char* wsb = (unsigned char*)d_ws;   // 1 MB bf16 hi/lo weight frags

  prep_w<<<dim3(128), dim3(256), 0, stream>>>(wg, wn, wsb);
  router_fused<<<dim3(NTOK / BM), dim3(1024), 0, stream>>>(x, eps, wsb,
                                                           (float*)d_out);
}

// Round 3
// 127.583 us; speedup vs baseline: 1.3780x; 1.0839x over previous
//
#include <hip/hip_runtime.h>
#include <math.h>

// Problem constants
#define DD    2048
#define EE    64
#define NTOK  8192
#define BM    32                // tokens per block
#define NKH   8                 // K split: 8 waves, 256 k each
#define NKS   16                // ksteps (16 k) per wave

// Output layout (all read back as float32 by harness)
#define PROB_OFF 0
#define IDX_OFF  524288
#define MASK_OFF 540672
#define MASK_K_STRIDE (NTOK * EE)

typedef __bf16 bf16x8 __attribute__((ext_vector_type(8)));
typedef float  f32x16 __attribute__((ext_vector_type(16)));

__device__ __forceinline__ unsigned f2bf_rne(float f) {
  unsigned u = __float_as_uint(f);
  return (u + 0x7fffu + ((u >> 16) & 1u)) >> 16;   // low 16 bits = bf16
}
__device__ __forceinline__ float bf2f(unsigned h) {
  return __uint_as_float(h << 16);
}

// ---------------------------------------------------------------------------
// prep_w: weights -> MFMA-fragment-ready bf16 hi/lo in workspace (1 MB).
// Fragment bijection (validated end-to-end by R1/R2 passes):
//   slot (g, nt, mat, lane, i)  <->  B[k][c],  k = 16*g + 8*(lane>>5) + i,
//   c = 32*nt + (lane&31),  (c<64 -> gate, else noise).
// Byte addr = ((g*4 + nt)*2 + mat)*1024 + lane*16 + 2*i.
// ---------------------------------------------------------------------------
__global__ __launch_bounds__(256) void prep_w(
    const float* __restrict__ wg, const float* __restrict__ wn,
    unsigned char* __restrict__ wsb)
{
  const int t  = blockIdx.x * 256 + threadIdx.x;   // 0..32767
  const int l  = t & 63;
  const int nt = (t >> 6) & 3;
  const int g  = t >> 8;                           // 0..127 (16-k steps)
  const int colg = nt * 32 + (l & 31);             // 0..127
  const int kb   = g * 16 + 8 * (l >> 5);
  const float* wsrc = (colg < EE) ? (wg + colg) : (wn + (colg - EE));

  unsigned hv[8], lv[8];
#pragma unroll
  for (int i = 0; i < 8; ++i) {
    const float v = wsrc[(size_t)(kb + i) * EE];
    const unsigned h = f2bf_rne(v);
    hv[i] = h;
    lv[i] = f2bf_rne(v - bf2f(h));
  }
  uint4 hq, lq;
  hq.x = hv[0] | (hv[1] << 16); hq.y = hv[2] | (hv[3] << 16);
  hq.z = hv[4] | (hv[5] << 16); hq.w = hv[6] | (hv[7] << 16);
  lq.x = lv[0] | (lv[1] << 16); lq.y = lv[2] | (lv[3] << 16);
  lq.z = lv[4] | (lv[5] << 16); lq.w = lv[6] | (lv[7] << 16);

  const size_t base = ((size_t)(g * 4 + nt) * 2) * 1024 + (size_t)l * 16;
  *reinterpret_cast<uint4*>(wsb + base)        = hq;   // hi
  *reinterpret_cast<uint4*>(wsb + base + 1024) = lq;   // lo
}

// ---------------------------------------------------------------------------
// router_fused v3: 256 blocks x 512 thr (8 independent waves). Wave kh owns
// the FULL 32tok x 128col tile over its 256-k slice (16 ksteps): per kstep
// 2 x-loads (fp32, line-exact across 32 rows) + 8 B-loads (L2-resident ws)
// + in-reg fp32->bf16 hi/lo + 12 mfma_32x32x16 (3-term hi/lo split).
// x is read exactly once chip-wide (no nt redundancy). 3-slot register
// pipeline, ~200 VGPR live under a 256-VGPR budget (launch_bounds(512,2))
// so the allocator cannot collapse it (the R2 failure). No barriers in the
// k-loop; 2-phase LDS kh-reduce + shuffle top-2 epilogue at the end.
// ---------------------------------------------------------------------------
struct Slot {
  float4 xa, xb;
  uint4 bh0, bl0, bh1, bl1, bh2, bl2, bh3, bl3;
};

union BF8 { bf16x8 v; ushort u[8]; };

__device__ __forceinline__ void cvt_hilo(const float4& a, const float4& b,
                                         bf16x8& hi, bf16x8& lo) {
  const float f[8] = {a.x, a.y, a.z, a.w, b.x, b.y, b.z, b.w};
  BF8 H, L;
#pragma unroll
  for (int i = 0; i < 8; ++i) {
    const unsigned u = __float_as_uint(f[i]);
    H.u[i] = (ushort)(u >> 16);                                 // exact prefix
    L.v[i] = (__bf16)(f[i] - __uint_as_float(u & 0xffff0000u)); // residual, RNE
  }
  hi = H.v; lo = L.v;
}

__device__ __forceinline__ bf16x8 bc(const uint4& q) {
  return __builtin_bit_cast(bf16x8, q);
}

__device__ __forceinline__ void load_slot(Slot& s, const float* xp,
                                          const unsigned char* bp, int ks) {
  const float* p = xp + 16 * ks;
  s.xa = *reinterpret_cast<const float4*>(p);
  s.xb = *reinterpret_cast<const float4*>(p + 4);
  const unsigned char* q = bp + (size_t)8192 * ks;
  s.bh0 = *reinterpret_cast<const uint4*>(q);
  s.bl0 = *reinterpret_cast<const uint4*>(q + 1024);
  s.bh1 = *reinterpret_cast<const uint4*>(q + 2048);
  s.bl1 = *reinterpret_cast<const uint4*>(q + 3072);
  s.bh2 = *reinterpret_cast<const uint4*>(q + 4096);
  s.bl2 = *reinterpret_cast<const uint4*>(q + 5120);
  s.bh3 = *reinterpret_cast<const uint4*>(q + 6144);
  s.bl3 = *reinterpret_cast<const uint4*>(q + 7168);
}

__device__ __forceinline__ void compute_slot(const Slot& s,
    f32x16& a0, f32x16& a1, f32x16& a2, f32x16& a3) {
  bf16x8 ahi, alo;
  cvt_hilo(s.xa, s.xb, ahi, alo);
  {
    const bf16x8 bh = bc(s.bh0), bl = bc(s.bl0);
    a0 = __builtin_amdgcn_mfma_f32_32x32x16_bf16(ahi, bh, a0, 0, 0, 0);
    a0 = __builtin_amdgcn_mfma_f32_32x32x16_bf16(ahi, bl, a0, 0, 0, 0);
    a0 = __builtin_amdgcn_mfma_f32_32x32x16_bf16(alo, bh, a0, 0, 0, 0);
  }
  {
    const bf16x8 bh = bc(s.bh1), bl = bc(s.bl1);
    a1 = __builtin_amdgcn_mfma_f32_32x32x16_bf16(ahi, bh, a1, 0, 0, 0);
    a1 = __builtin_amdgcn_mfma_f32_32x32x16_bf16(ahi, bl, a1, 0, 0, 0);
    a1 = __builtin_amdgcn_mfma_f32_32x32x16_bf16(alo, bh, a1, 0, 0, 0);
  }
  {
    const bf16x8 bh = bc(s.bh2), bl = bc(s.bl2);
    a2 = __builtin_amdgcn_mfma_f32_32x32x16_bf16(ahi, bh, a2, 0, 0, 0);
    a2 = __builtin_amdgcn_mfma_f32_32x32x16_bf16(ahi, bl, a2, 0, 0, 0);
    a2 = __builtin_amdgcn_mfma_f32_32x32x16_bf16(alo, bh, a2, 0, 0, 0);
  }
  {
    const bf16x8 bh = bc(s.bh3), bl = bc(s.bl3);
    a3 = __builtin_amdgcn_mfma_f32_32x32x16_bf16(ahi, bh, a3, 0, 0, 0);
    a3 = __builtin_amdgcn_mfma_f32_32x32x16_bf16(ahi, bl, a3, 0, 0, 0);
    a3 = __builtin_amdgcn_mfma_f32_32x32x16_bf16(alo, bh, a3, 0, 0, 0);
  }
}

__global__ __launch_bounds__(512, 2) void router_fused(
    const float* __restrict__ x,
    const float* __restrict__ noise_eps,
    const unsigned char* __restrict__ wsb,
    float* __restrict__ out)
{
  __shared__ float Lp[4][BM][128];   // 64 KB kh-partials; used post-loop only

  const int tid  = threadIdx.x;
  const int wid  = tid >> 6;          // 0..7  = kh
  const int lane = tid & 63;
  const int kh   = wid;
  const int tok0 = blockIdx.x * BM;

  // A source: lane l -> x[tok0+(l&31)][kh*256 + 16*s + 8*(l>>5) + 0..7]
  const float* xp = x + (size_t)(tok0 + (lane & 31)) * DD
                      + kh * 256 + 8 * (lane >> 5);
  // B source: g = kh*16 + s; bytes g*8192 + nt*2048 + mat*1024 + lane*16
  const unsigned char* bp = wsb + (size_t)(kh * 16) * 8192 + (size_t)lane * 16;

  f32x16 a0 = {0.f,0.f,0.f,0.f,0.f,0.f,0.f,0.f,0.f,0.f,0.f,0.f,0.f,0.f,0.f,0.f};
  f32x16 a1 = a0, a2 = a0, a3 = a0;

  // 3-slot round-robin register pipeline, prefetch distance 2 full ksteps.
  Slot s0, s1, s2;
  load_slot(s0, xp, bp, 0);
  load_slot(s1, xp, bp, 1);
  load_slot(s2, xp, bp, 2);

#pragma unroll
  for (int s = 0; s < NKS; ++s) {
    Slot& cur = (s % 3 == 0) ? s0 : (s % 3 == 1) ? s1 : s2;
    compute_slot(cur, a0, a1, a2, a3);
    if (s + 3 < NKS) load_slot(cur, xp, bp, s + 3);
  }

  // ---- kh-reduce, 2 phases: kh 0..3 write slabs, kh 4..7 add ----
  // C/D map (validated R1/R2): col = lane&31,
  // row = (q&3) + 8*(q>>2) + 4*(lane>>5)
  const int ccol0 = lane & 31;
  const int crow0 = 4 * (lane >> 5);
  if (wid < 4) {
#pragma unroll
    for (int q = 0; q < 16; ++q) {
      const int row = (q & 3) + 8 * (q >> 2) + crow0;
      Lp[wid][row][ccol0]      = a0[q];
      Lp[wid][row][32 + ccol0] = a1[q];
      Lp[wid][row][64 + ccol0] = a2[q];
      Lp[wid][row][96 + ccol0] = a3[q];
    }
  }
  __syncthreads();
  if (wid >= 4) {
#pragma unroll
    for (int q = 0; q < 16; ++q) {
      const int row = (q & 3) + 8 * (q >> 2) + crow0;
      Lp[wid - 4][row][ccol0]      += a0[q];
      Lp[wid - 4][row][32 + ccol0] += a1[q];
      Lp[wid - 4][row][64 + ccol0] += a2[q];
      Lp[wid - 4][row][96 + ccol0] += a3[q];
    }
  }
  __syncthreads();

  // ---- epilogue: 8 waves x 4 tokens; lane = expert ----
#pragma unroll
  for (int it = 0; it < 4; ++it) {
    const int tl  = wid * 4 + it;
    const int tok = tok0 + tl;

    const float g    = Lp[0][tl][lane] + Lp[1][tl][lane]
                     + Lp[2][tl][lane] + Lp[3][tl][lane];
    const float nraw = Lp[0][tl][64 + lane] + Lp[1][tl][64 + lane]
                     + Lp[2][tl][64 + lane] + Lp[3][tl][64 + lane];
    const float ep   = noise_eps[(size_t)tok * EE + lane];

    const float sp = fmaxf(nraw, 0.0f) + log1pf(expf(-fabsf(nraw)));
    const float z  = fmaf(sp, ep, g);

    float v1 = z; int i1 = lane;
#pragma unroll
    for (int off = 32; off >= 1; off >>= 1) {
      const float ov = __shfl_xor(v1, off, 64);
      const int   oi = __shfl_xor(i1, off, 64);
      if (ov > v1 || (ov == v1 && oi < i1)) { v1 = ov; i1 = oi; }
    }
    float v2 = (lane == i1) ? -INFINITY : z; int i2 = lane;
#pragma unroll
    for (int off = 32; off >= 1; off >>= 1) {
      const float ov = __shfl_xor(v2, off, 64);
      const int   oi = __shfl_xor(i2, off, 64);
      if (ov > v2 || (ov == v2 && oi < i2)) { v2 = ov; i2 = oi; }
    }

    const float e2 = expf(v2 - v1);
    const float denom = 1.0f + e2;
    const float p1 = 1.0f / denom;
    const float p2 = e2 / denom;

    out[PROB_OFF + (size_t)tok * EE + lane] =
        (lane == i1) ? p1 : ((lane == i2) ? p2 : 0.0f);
    if (lane == 0) {
      out[IDX_OFF + tok * 2 + 0] = (float)i1;
      out[IDX_OFF + tok * 2 + 1] = (float)i2;
    }
    out[MASK_OFF + 0 * MASK_K_STRIDE + (size_t)tok * EE + lane] =
        (lane == i1) ? 1.0f : 0.0f;
    out[MASK_OFF + 1 * MASK_K_STRIDE + (size_t)tok * EE + lane] =
        (lane == i2) ? 1.0f : 0.0f;
  }
}

// ---------------------------------------------------------------------------
extern "C" void kernel_launch(void* const* d_in, const int* in_sizes, int n_in,
                              void* d_out, int out_size, void* d_ws, size_t ws_size,
                              hipStream_t stream) {
  const float* x   = (const float*)d_in[0];
  const float* eps = (const float*)d_in[1];
  const float* wg  = (const float*)d_in[2];
  const float* wn  = (const float*)d_in[3];
  unsigned char* wsb = (unsigned char*)d_ws;   // 1 MB bf16 hi/lo weight frags

  prep_w<<<dim3(128), dim3(256), 0, stream>>>(wg, wn, wsb);
  router_fused<<<dim3(NTOK / BM), dim3(512), 0, stream>>>(x, eps, wsb,
                                                          (float*)d_out);
}